// Round 1
// baseline (420.482 us; speedup 1.0000x reference)
//
#include <hip/hip_runtime.h>

#define IN_CH  16
#define HID    8
#define OUT_CH 4
#define N_MID  60
#define BATCH  4194304

// ---------------------------------------------------------------------------
// Kernel 1: fold the 62-layer affine chain into a single [4,16] matrix + [4]
// bias, written to d_ws (68 floats). One block, 128 threads: thread t owns
// element (t>>4, t&15) of the running [8,16] matrix A (A = W_l ... W1).
// Double-buffered LDS, one barrier per layer.
// ---------------------------------------------------------------------------
__global__ __launch_bounds__(128) void fold_kernel(
    const float* __restrict__ W1, const float* __restrict__ b1,
    const float* __restrict__ Ws, const float* __restrict__ bs,
    const float* __restrict__ W2, const float* __restrict__ b2,
    float* __restrict__ Mc /* [4*16 + 4] */) {

    __shared__ float A[2][HID][IN_CH];   // running matrix
    __shared__ float d[2][HID];          // running bias

    const int t   = threadIdx.x;         // 0..127
    const int r   = t >> 4;              // 0..7
    const int col = t & 15;              // 0..15

    // init: A = W1 ([8,16] row-major), d = b1
    A[0][r][col] = W1[r * IN_CH + col];
    if (t < HID) d[0][t] = b1[t];
    __syncthreads();

    int cur = 0;
    for (int l = 0; l < N_MID; ++l) {
        const float* W = Ws + l * HID * HID;   // [8][8] row-major
        float acc = 0.f;
        #pragma unroll
        for (int k = 0; k < HID; ++k)
            acc += W[r * HID + k] * A[cur][k][col];
        A[1 - cur][r][col] = acc;
        if (t < HID) {
            float bc = bs[l * HID + t];
            #pragma unroll
            for (int k = 0; k < HID; ++k)
                bc += W[t * HID + k] * d[cur][k];
            d[1 - cur][t] = bc;
        }
        cur = 1 - cur;
        __syncthreads();
    }

    // final: Mf = W2 @ A  -> [4,16];  cf = W2 @ d + b2 -> [4]
    if (t < OUT_CH * IN_CH) {
        const int rr = t >> 4, cc = t & 15;
        float acc = 0.f;
        #pragma unroll
        for (int k = 0; k < HID; ++k)
            acc += W2[rr * HID + k] * A[cur][k][cc];
        Mc[rr * IN_CH + cc] = acc;
    }
    if (t < OUT_CH) {
        float acc = b2[t];
        #pragma unroll
        for (int k = 0; k < HID; ++k)
            acc += W2[t * HID + k] * d[cur][k];
        Mc[OUT_CH * IN_CH + t] = acc;
    }
}

// ---------------------------------------------------------------------------
// Kernel 2: out[i] = Mf @ x[i] + cf for each batch row. One thread per row:
// 4x float4 loads (contiguous 64B per lane), 64 FMAs vs LDS-broadcast
// folded weights, 1x float4 store. Memory-bound by design.
// ---------------------------------------------------------------------------
__global__ __launch_bounds__(256) void apply_kernel(
    const float* __restrict__ x,
    const float* __restrict__ Mc,
    float* __restrict__ out) {

    __shared__ float sM[OUT_CH * IN_CH + OUT_CH];
    if (threadIdx.x < OUT_CH * IN_CH + OUT_CH) sM[threadIdx.x] = Mc[threadIdx.x];
    __syncthreads();

    const size_t i = (size_t)blockIdx.x * blockDim.x + threadIdx.x;
    if (i >= (size_t)BATCH) return;

    const float4* xp = (const float4*)(x + i * IN_CH);
    float4 v0 = xp[0], v1 = xp[1], v2 = xp[2], v3 = xp[3];
    float xv[IN_CH] = { v0.x, v0.y, v0.z, v0.w,
                        v1.x, v1.y, v1.z, v1.w,
                        v2.x, v2.y, v2.z, v2.w,
                        v3.x, v3.y, v3.z, v3.w };

    float o[OUT_CH];
    #pragma unroll
    for (int rr = 0; rr < OUT_CH; ++rr) {
        float acc = sM[OUT_CH * IN_CH + rr];
        #pragma unroll
        for (int k = 0; k < IN_CH; ++k)
            acc += sM[rr * IN_CH + k] * xv[k];
        o[rr] = acc;
    }
    ((float4*)out)[i] = make_float4(o[0], o[1], o[2], o[3]);
}

extern "C" void kernel_launch(void* const* d_in, const int* in_sizes, int n_in,
                              void* d_out, int out_size, void* d_ws, size_t ws_size,
                              hipStream_t stream) {
    const float* x  = (const float*)d_in[0];
    const float* W1 = (const float*)d_in[1];
    const float* b1 = (const float*)d_in[2];
    const float* Ws = (const float*)d_in[3];
    const float* bs = (const float*)d_in[4];
    const float* W2 = (const float*)d_in[5];
    const float* b2 = (const float*)d_in[6];
    float* out = (float*)d_out;
    float* Mc  = (float*)d_ws;   // 68 floats

    fold_kernel<<<1, 128, 0, stream>>>(W1, b1, Ws, bs, W2, b2, Mc);

    const int threads = 256;
    const int blocks  = BATCH / threads;   // 4194304 / 256 = 16384, exact
    apply_kernel<<<blocks, threads, 0, stream>>>(x, Mc, out);
}

// Round 2
// 395.966 us; speedup vs baseline: 1.0619x; 1.0619x over previous
//
#include <hip/hip_runtime.h>

#define IN_CH  16
#define HID    8
#define OUT_CH 4
#define N_MID  60
#define BATCH  4194304

// ---------------------------------------------------------------------------
// Kernel 1: fold the 62-layer affine chain into [4,16] matrix + [4] bias in
// d_ws. All Ws/bs staged into LDS first (coalesced, ~17 KB) so the 60-layer
// dependent chain never touches global memory.
// ---------------------------------------------------------------------------
__global__ __launch_bounds__(128) void fold_kernel(
    const float* __restrict__ W1, const float* __restrict__ b1,
    const float* __restrict__ Ws, const float* __restrict__ bs,
    const float* __restrict__ W2, const float* __restrict__ b2,
    float* __restrict__ Mc /* [4*16 + 4] */) {

    __shared__ float sWs[N_MID * HID * HID];   // 15360 B
    __shared__ float sbs[N_MID * HID];         //  1920 B
    __shared__ float A[2][HID][IN_CH];         // running matrix (double buf)
    __shared__ float d[2][HID];                // running bias

    const int t   = threadIdx.x;   // 0..127
    const int r   = t >> 4;        // 0..7
    const int col = t & 15;        // 0..15

    // Stage all mid-layer weights/biases into LDS (coalesced dword loads).
    for (int i = t; i < N_MID * HID * HID; i += 128) sWs[i] = Ws[i];
    for (int i = t; i < N_MID * HID;       i += 128) sbs[i] = bs[i];

    // init: A = W1 ([8,16] row-major), d = b1
    A[0][r][col] = W1[r * IN_CH + col];
    if (t < HID) d[0][t] = b1[t];
    __syncthreads();

    int cur = 0;
    for (int l = 0; l < N_MID; ++l) {
        const float* W = sWs + l * HID * HID;   // [8][8] row-major in LDS
        float acc = 0.f;
        #pragma unroll
        for (int k = 0; k < HID; ++k)
            acc += W[r * HID + k] * A[cur][k][col];
        A[1 - cur][r][col] = acc;
        if (t < HID) {
            float bc = sbs[l * HID + t];
            #pragma unroll
            for (int k = 0; k < HID; ++k)
                bc += W[t * HID + k] * d[cur][k];
            d[1 - cur][t] = bc;
        }
        cur = 1 - cur;
        __syncthreads();
    }

    // final: Mf = W2 @ A -> [4,16];  cf = W2 @ d + b2 -> [4]
    if (t < OUT_CH * IN_CH) {
        const int rr = t >> 4, cc = t & 15;
        float acc = 0.f;
        #pragma unroll
        for (int k = 0; k < HID; ++k)
            acc += W2[rr * HID + k] * A[cur][k][cc];
        Mc[rr * IN_CH + cc] = acc;
    }
    if (t < OUT_CH) {
        float acc = b2[t];
        #pragma unroll
        for (int k = 0; k < HID; ++k)
            acc += W2[t * HID + k] * d[cur][k];
        Mc[OUT_CH * IN_CH + t] = acc;
    }
}

// ---------------------------------------------------------------------------
// Kernel 2: out[i] = Mf @ x[i] + cf. Quad-cooperative: 4 lanes per row.
// Lane l loads float4 #g (lane-stride 16 B -> perfectly coalesced: one wave
// = 1 KB contiguous per load instruction), computes 4 output partials for
// its quadrant of the row, butterfly-reduces across the quad with
// __shfl_xor(1) and __shfl_xor(2), then stores one dword (wave = 256 B
// contiguous).
// ---------------------------------------------------------------------------
__global__ __launch_bounds__(256) void apply_kernel(
    const float* __restrict__ x,
    const float* __restrict__ Mc,
    float* __restrict__ out) {

    const int tid = threadIdx.x;
    const size_t g = (size_t)blockIdx.x * 256 + tid;   // float4 index into x
    const int q = tid & 3;                             // quadrant within row

    // Per-thread folded-weight slice: M[rr][4q..4q+3] for rr=0..3, + bias.
    // 5 broadcast-ish loads; all threads in a wave hit the same few lines.
    const float4* M4 = (const float4*)Mc;
    const float4 m0 = M4[0 * 4 + q];
    const float4 m1 = M4[1 * 4 + q];
    const float4 m2 = M4[2 * 4 + q];
    const float4 m3 = M4[3 * 4 + q];
    const float  cb = Mc[OUT_CH * IN_CH + q];

    const float4 xv = ((const float4*)x)[g];

    float p0 = m0.x * xv.x + m0.y * xv.y + m0.z * xv.z + m0.w * xv.w;
    float p1 = m1.x * xv.x + m1.y * xv.y + m1.z * xv.z + m1.w * xv.w;
    float p2 = m2.x * xv.x + m2.y * xv.y + m2.z * xv.z + m2.w * xv.w;
    float p3 = m3.x * xv.x + m3.y * xv.y + m3.z * xv.z + m3.w * xv.w;

    // Butterfly sum across the 4-lane quad (masks 1 and 2 stay in-quad).
    p0 += __shfl_xor(p0, 1); p1 += __shfl_xor(p1, 1);
    p2 += __shfl_xor(p2, 1); p3 += __shfl_xor(p3, 1);
    p0 += __shfl_xor(p0, 2); p1 += __shfl_xor(p1, 2);
    p2 += __shfl_xor(p2, 2); p3 += __shfl_xor(p3, 2);

    const float val = (q == 0 ? p0 : q == 1 ? p1 : q == 2 ? p2 : p3) + cb;
    out[g] = val;   // out[row*4 + q] == out[g]
}

extern "C" void kernel_launch(void* const* d_in, const int* in_sizes, int n_in,
                              void* d_out, int out_size, void* d_ws, size_t ws_size,
                              hipStream_t stream) {
    const float* x  = (const float*)d_in[0];
    const float* W1 = (const float*)d_in[1];
    const float* b1 = (const float*)d_in[2];
    const float* Ws = (const float*)d_in[3];
    const float* bs = (const float*)d_in[4];
    const float* W2 = (const float*)d_in[5];
    const float* b2 = (const float*)d_in[6];
    float* out = (float*)d_out;
    float* Mc  = (float*)d_ws;   // 68 floats

    fold_kernel<<<1, 128, 0, stream>>>(W1, b1, Ws, bs, W2, b2, Mc);

    // BATCH*IN_CH/4 float4s of x, one per thread, 256 threads/block.
    const int blocks = (BATCH * (IN_CH / 4)) / 256;   // 65536
    apply_kernel<<<blocks, 256, 0, stream>>>(x, Mc, out);
}

// Round 4
// 395.647 us; speedup vs baseline: 1.0628x; 1.0008x over previous
//
#include <hip/hip_runtime.h>

#define IN_CH  16
#define HID    8
#define OUT_CH 4
#define N_MID  60
#define BATCH  4194304

// Native clang vector type: __builtin_nontemporal_load/store accept these
// (HIP_vector_type float4 is a struct and is rejected).
typedef float vfloat4 __attribute__((ext_vector_type(4)));

// ---------------------------------------------------------------------------
// Kernel 1: fold the 62-layer affine chain into [4,16] matrix + [4] bias in
// d_ws. Single wave (64 threads): __syncthreads lowers to waitcnt only.
// All Ws/bs staged into LDS with float4 loads first; the 60-layer dependent
// chain runs entirely from LDS, one barrier per layer (double-buffered A).
// ---------------------------------------------------------------------------
__global__ __launch_bounds__(64) void fold_kernel(
    const float* __restrict__ W1, const float* __restrict__ b1,
    const float* __restrict__ Ws, const float* __restrict__ bs,
    const float* __restrict__ W2, const float* __restrict__ b2,
    float* __restrict__ Mc /* [4*16 + 4] */) {

    __shared__ float sWs[N_MID * HID * HID];   // 15360 B
    __shared__ float sbs[N_MID * HID];         //  1920 B
    __shared__ float A[2][HID][IN_CH];         // running matrix (double buf)
    __shared__ float d[2][HID];                // running bias

    const int t   = threadIdx.x;   // 0..63
    const int col = t & 15;        // 0..15
    const int r0  = t >> 4;        // 0..3 ; thread owns rows r0 and r0+4

    // Stage mid-layer weights/biases into LDS, float4-vectorized.
    {
        const float4* Ws4  = (const float4*)Ws;
        float4*       sW4  = (float4*)sWs;
        #pragma unroll 1
        for (int i = t; i < N_MID * HID * HID / 4; i += 64) sW4[i] = Ws4[i];
        const float4* bs4  = (const float4*)bs;
        float4*       sb4  = (float4*)sbs;
        for (int i = t; i < N_MID * HID / 4; i += 64) sb4[i] = bs4[i];
    }

    // init: A = W1 ([8,16] row-major), d = b1
    A[0][r0][col]     = W1[r0 * IN_CH + col];
    A[0][r0 + 4][col] = W1[(r0 + 4) * IN_CH + col];
    if (t < HID) d[0][t] = b1[t];
    __syncthreads();

    int cur = 0;
    for (int l = 0; l < N_MID; ++l) {
        const float* W = sWs + l * HID * HID;   // [8][8] row-major in LDS
        float a0 = 0.f, a1 = 0.f;
        #pragma unroll
        for (int k = 0; k < HID; ++k) {
            const float av = A[cur][k][col];
            a0 += W[r0 * HID + k]       * av;
            a1 += W[(r0 + 4) * HID + k] * av;
        }
        float bc = 0.f;
        if (t < HID) {
            bc = sbs[l * HID + t];
            #pragma unroll
            for (int k = 0; k < HID; ++k)
                bc += W[t * HID + k] * d[cur][k];
        }
        // write other buffer; reads of A[cur] already done (program order)
        A[1 - cur][r0][col]     = a0;
        A[1 - cur][r0 + 4][col] = a1;
        if (t < HID) d[1 - cur][t] = bc;
        cur ^= 1;
        __syncthreads();   // single barrier per layer (double buffer)
    }

    // final: Mf = W2 @ A -> [4,16] (64 threads cover it exactly)
    {
        const int rr = t >> 4, cc = t & 15;
        float acc = 0.f;
        #pragma unroll
        for (int k = 0; k < HID; ++k)
            acc += W2[rr * HID + k] * A[cur][k][cc];
        Mc[rr * IN_CH + cc] = acc;
    }
    if (t < OUT_CH) {
        float acc = b2[t];
        #pragma unroll
        for (int k = 0; k < HID; ++k)
            acc += W2[t * HID + k] * d[cur][k];
        Mc[OUT_CH * IN_CH + t] = acc;
    }
}

// ---------------------------------------------------------------------------
// Kernel 2: out[i] = Mf @ x[i] + cf. Quad-cooperative, grid-stride x8.
// Lane q of each 4-lane quad loads one float4 (lane-stride 16 B: wave = 1 KB
// contiguous per load), computes the 4 output partials for its quadrant,
// then a 3-shuffle reduce-scatter leaves exactly output q in lane q, stored
// as one contiguous dword per lane. All 8 x-loads issued before compute for
// MLP; nontemporal hints since x/out are pure streaming.
// ---------------------------------------------------------------------------
#define ITERS 8

__global__ __launch_bounds__(256) void apply_kernel(
    const float* __restrict__ x,
    const float* __restrict__ Mc,
    float* __restrict__ out) {

    const int tid = threadIdx.x;
    const int q   = tid & 3;

    // Per-thread folded-weight slice: M[rr][4q..4q+3] for rr=0..3, + bias q.
    const float4* M4 = (const float4*)Mc;
    const float4 m0 = M4[0 * 4 + q];
    const float4 m1 = M4[1 * 4 + q];
    const float4 m2 = M4[2 * 4 + q];
    const float4 m3 = M4[3 * 4 + q];
    const float  cb = Mc[OUT_CH * IN_CH + q];

    const vfloat4* __restrict__ x4 = (const vfloat4*)x;
    const size_t g0     = (size_t)blockIdx.x * 256 + tid;
    const size_t stride = (size_t)gridDim.x * 256;

    vfloat4 xv[ITERS];
    #pragma unroll
    for (int j = 0; j < ITERS; ++j)
        xv[j] = __builtin_nontemporal_load(&x4[g0 + j * stride]);

    const bool hi2 = (q & 2) != 0;
    const bool lo1 = (q & 1) != 0;

    #pragma unroll
    for (int j = 0; j < ITERS; ++j) {
        const vfloat4 v = xv[j];
        float p0 = m0.x * v.x + m0.y * v.y + m0.z * v.z + m0.w * v.w;
        float p1 = m1.x * v.x + m1.y * v.y + m1.z * v.z + m1.w * v.w;
        float p2 = m2.x * v.x + m2.y * v.y + m2.z * v.z + m2.w * v.w;
        float p3 = m3.x * v.x + m3.y * v.y + m3.z * v.z + m3.w * v.w;

        // Reduce-scatter across the quad: 3 shuffles instead of 8.
        // Round 1 (xor 2): keep outputs {q&2, (q&2)+1}, send the other two.
        float send_a = hi2 ? p0 : p2;
        float send_b = hi2 ? p1 : p3;
        float recv_a = __shfl_xor(send_a, 2);
        float recv_b = __shfl_xor(send_b, 2);
        float k0 = (hi2 ? p2 : p0) + recv_a;   // output (q&2)
        float k1 = (hi2 ? p3 : p1) + recv_b;   // output (q&2)+1
        // Round 2 (xor 1): keep output q.
        float send = lo1 ? k0 : k1;
        float recv = __shfl_xor(send, 1);
        float val  = (lo1 ? k1 : k0) + recv + cb;

        __builtin_nontemporal_store(val, &out[g0 + j * stride]);
    }
}

extern "C" void kernel_launch(void* const* d_in, const int* in_sizes, int n_in,
                              void* d_out, int out_size, void* d_ws, size_t ws_size,
                              hipStream_t stream) {
    const float* x  = (const float*)d_in[0];
    const float* W1 = (const float*)d_in[1];
    const float* b1 = (const float*)d_in[2];
    const float* Ws = (const float*)d_in[3];
    const float* bs = (const float*)d_in[4];
    const float* W2 = (const float*)d_in[5];
    const float* b2 = (const float*)d_in[6];
    float* out = (float*)d_out;
    float* Mc  = (float*)d_ws;   // 68 floats

    fold_kernel<<<1, 64, 0, stream>>>(W1, b1, Ws, bs, W2, b2, Mc);

    // BATCH*IN_CH/4 float4s of x; ITERS per thread, 256 threads/block.
    const int blocks = (BATCH * (IN_CH / 4)) / (256 * ITERS);   // 8192
    apply_kernel<<<blocks, 256, 0, stream>>>(x, Mc, out);
}